// Round 1
// 604.900 us; speedup vs baseline: 1.4325x; 1.4325x over previous
//
#include <hip/hip_runtime.h>
#include <cstdint>

typedef unsigned short u16;
typedef __attribute__((ext_vector_type(8))) short bf16x8;
typedef __attribute__((ext_vector_type(4))) float f32x4;

#define DIM   1024
#define BATCH 4
#define SEQ   4096
#define E3    3072
#define MTOT  (BATCH*SEQ)   // 16384

// ---------- bf16 helpers (RNE) ----------
__device__ __forceinline__ u16 f2bf(float x) {
    union { float f; unsigned u; } v; v.f = x;
    unsigned r = v.u + 0x7FFFu + ((v.u >> 16) & 1u);
    return (u16)(r >> 16);
}

// ---------- async global->LDS 16B ----------
__device__ __forceinline__ void gl16(const void* g, void* l) {
    __builtin_amdgcn_global_load_lds(
        (const __attribute__((address_space(1))) void*)g,
        (__attribute__((address_space(3))) void*)l, 16, 0, 0);
}

// ---------------------------------------------------------------------------
// GEMM mainloop: C[256x256] += A * B^T, both bf16 k-major, K mult of 32,
// K/32 >= 4. 512 thr = 8 waves (2m x 4n); per-wave 128x64 -> acc[8][4].
//
// LDS: 4-deep ring of 32KB K-tiles (A 16KB + B 16KB), fragment-identity
// chunks: chunk q holds, at lane offset L*16B, A[m0+q*16+(L&15)][k0+(L>>4)*8
// ..+8) -- so ds_read_b128 is linear & conflict-free, and global_load_lds's
// linear dest matches (per-lane pre-swizzled global source).
//
// Pipeline (T3+T4): stage tile t+3 while computing tile t; per-tile sync is
// counted s_waitcnt vmcnt(8) + RAW s_barrier (never drain to 0 in the loop).
// vmcnt(8): own 4 gl16 of tiles t+1,t+2 outstanding -> tile t's complete;
// barrier then publishes all waves' tile-t stages. Overwrite hazard: stage
// of t+3 lands in tile t-1's slot; every wave's ds_reads of t-1 completed
// (lgkmcnt before its MFMAs) before its iter-t barrier, and the stage is
// issued after that barrier -> safe.
// ---------------------------------------------------------------------------
__device__ __forceinline__ void gemm256(
    const u16* __restrict__ A, int sA,
    const u16* __restrict__ B, int sB,
    int K, int m0, int n0,
    u16* lds, f32x4 acc[8][4])
{
    const int t   = threadIdx.x;
    const int w   = t >> 6, L = t & 63;
    const int rL  = L & 15, kq = L >> 4;
    const int qa  = 2*w;          // this wave's stage chunk pair (A and B)
    const int ia0 = 8*(w>>2);     // A-frag tile base (m)
    const int jb0 = 4*(w&3);      // B-frag tile base (n)

    const size_t ga0 = (size_t)(m0 + qa*16 + rL)*sA + kq*8;
    const size_t ga1 = ga0 + (size_t)16*sA;
    const size_t gb0 = (size_t)(n0 + qa*16 + rL)*sB + kq*8;
    const size_t gb1 = gb0 + (size_t)16*sB;

#define RING_STAGE(tile) { \
    const size_t k0 = (size_t)(tile)*32; \
    u16* sb = lds + ((tile)&3)*16384; \
    gl16(A + ga0 + k0, sb + qa*512); \
    gl16(A + ga1 + k0, sb + qa*512 + 512); \
    gl16(B + gb0 + k0, sb + 8192 + qa*512); \
    gl16(B + gb1 + k0, sb + 8192 + qa*512 + 512); }

#define RING_SYNC(N) \
    asm volatile("s_waitcnt vmcnt(" #N ")" ::: "memory"); \
    __builtin_amdgcn_s_barrier(); \
    asm volatile("" ::: "memory");

#define RING_COMPUTE(tile) { \
    const u16* sb = lds + ((tile)&3)*16384; \
    bf16x8 av[8], bv[4]; \
    _Pragma("unroll") \
    for (int i = 0; i < 8; ++i) av[i] = *(const bf16x8*)&sb[(ia0+i)*512 + L*8]; \
    _Pragma("unroll") \
    for (int j = 0; j < 4; ++j) bv[j] = *(const bf16x8*)&sb[8192 + (jb0+j)*512 + L*8]; \
    _Pragma("unroll") \
    for (int i = 0; i < 8; ++i) \
        _Pragma("unroll") \
        for (int j = 0; j < 4; ++j) \
            acc[i][j] = __builtin_amdgcn_mfma_f32_16x16x32_bf16(av[i], bv[j], acc[i][j], 0,0,0); }

    RING_STAGE(0); RING_STAGE(1); RING_STAGE(2);
    const int NT = K >> 5;
    for (int tt = 0; tt < NT-3; ++tt) {
        RING_SYNC(8);
        RING_STAGE(tt+3);
        RING_COMPUTE(tt);
    }
    RING_SYNC(8); RING_COMPUTE(NT-3);
    RING_SYNC(4); RING_COMPUTE(NT-2);
    RING_SYNC(0); RING_COMPUTE(NT-1);

#undef RING_STAGE
#undef RING_SYNC
#undef RING_COMPUTE
}

// ---------------------------------------------------------------------------
// elementwise: fp32 -> bf16
// ---------------------------------------------------------------------------
__global__ __launch_bounds__(256)
void cvt_bf16(const float* __restrict__ x, u16* __restrict__ y) {
    size_t i = ((size_t)blockIdx.x*256 + threadIdx.x)*4;
    float4 v = *(const float4*)&x[i];
    ushort4 h;
    h.x = f2bf(v.x); h.y = f2bf(v.y); h.z = f2bf(v.z); h.w = f2bf(v.w);
    *(ushort4*)&y[i] = h;
}

// ---------------------------------------------------------------------------
// QKV GEMM: A = Xbf, B = Wbf. Epilogue:
//   Q region: pre-scaled by 1/32, bf16, row-major  (pair-packed u32 stores)
//   K region: bf16, row-major                      (pair-packed u32 stores)
//   V region: bf16, transposed [b][d][s]           (ushort4 stores)
// ---------------------------------------------------------------------------
__global__ __launch_bounds__(512,2)
void gemm_qkv(const u16* __restrict__ Xbf, const u16* __restrict__ Wbf,
              const float* __restrict__ bias,
              u16* __restrict__ Qh, u16* __restrict__ Kh,
              u16* __restrict__ Vth)
{
    __shared__ __align__(16) u16 lds[65536];   // 128 KB ring
    f32x4 acc[8][4];
    #pragma unroll
    for (int i=0;i<8;++i)
        #pragma unroll
        for (int j=0;j<4;++j) acc[i][j] = (f32x4){0.f,0.f,0.f,0.f};

    const int m0 = blockIdx.y*256, n0 = blockIdx.x*256;
    gemm256(Xbf, DIM, Wbf, DIM, DIM, m0, n0, lds, acc);

    const int t = threadIdx.x, w = t>>6, L = t&63;
    const int wm = 128*(w>>2), wn = 64*(w&3);
    const int cl = L&15, rq = (L>>4)*4;
    const int region = n0 >> 10;           // whole 256-block in one region
    const float qscale = 0.03125f;

    if (region < 2) {
        u16* Dst = region ? Kh : Qh;
        const float fs = region ? 1.0f : qscale;
        #pragma unroll
        for (int j = 0; j < 4; ++j) {
            float bc = bias[n0 + wn + j*16 + cl];
            #pragma unroll
            for (int i = 0; i < 8; ++i)
                #pragma unroll
                for (int r = 0; r < 4; ++r)
                    acc[i][j][r] = (acc[i][j][r] + bc)*fs;
        }
        const int d0 = (n0 & 1023) + wn;
        #pragma unroll
        for (int p = 0; p < 2; ++p) {
            const int nt0 = 2*p, nt1 = 2*p+1;
            #pragma unroll
            for (int i = 0; i < 8; ++i) {
                int row0 = m0 + wm + i*16 + rq;
                int bi = row0 >> 12, s0 = row0 & (SEQ-1);
                #pragma unroll
                for (int r = 0; r < 4; ++r) {
                    float v0 = acc[i][nt0][r], v1 = acc[i][nt1][r];
                    float x0 = __shfl_xor(v0, 1, 64);
                    float x1 = __shfl_xor(v1, 1, 64);
                    unsigned wv; int colb;
                    if ((cl & 1) == 0) {
                        wv   = (unsigned)f2bf(v0) | ((unsigned)f2bf(x0) << 16);
                        colb = nt0*16 + cl;
                    } else {
                        wv   = (unsigned)f2bf(x1) | ((unsigned)f2bf(v1) << 16);
                        colb = nt1*16 + (cl-1);
                    }
                    size_t idx = ((size_t)bi*SEQ + s0 + r)*DIM + d0 + colb;
                    *(unsigned*)&Dst[idx] = wv;
                }
            }
        }
    } else {
        #pragma unroll
        for (int j = 0; j < 4; ++j) {
            int col = n0 + wn + j*16 + cl;
            float bc = bias[col];
            int d = col & (DIM-1);
            #pragma unroll
            for (int i = 0; i < 8; ++i) {
                int row0 = m0 + wm + i*16 + rq;
                int bi = row0 >> 12, s0 = row0 & (SEQ-1);
                ushort4 hv;
                hv.x = f2bf(acc[i][j][0] + bc);
                hv.y = f2bf(acc[i][j][1] + bc);
                hv.z = f2bf(acc[i][j][2] + bc);
                hv.w = f2bf(acc[i][j][3] + bc);
                size_t base = ((size_t)bi*DIM + d)*SEQ + s0;
                *(ushort4*)&Vth[base] = hv;
            }
        }
    }
}

// ---------------------------------------------------------------------------
// Scores, all batches: S_b = Qscaled_b @ K_b^T -> bf16, pair-packed stores.
// ---------------------------------------------------------------------------
__global__ __launch_bounds__(512,2)
void gemm_scores(const u16* __restrict__ Qh, const u16* __restrict__ Kh,
                 u16* __restrict__ S0, u16* __restrict__ S1,
                 u16* __restrict__ S2, u16* __restrict__ S3)
{
    __shared__ __align__(16) u16 lds[65536];
    f32x4 acc[8][4];
    #pragma unroll
    for (int i=0;i<8;++i)
        #pragma unroll
        for (int j=0;j<4;++j) acc[i][j] = (f32x4){0.f,0.f,0.f,0.f};

    const int bz = blockIdx.z;
    const size_t qo = (size_t)bz*SEQ*DIM;
    const int m0 = blockIdx.y*256, n0 = blockIdx.x*256;
    gemm256(Qh + qo, DIM, Kh + qo, DIM, DIM, m0, n0, lds, acc);

    u16* Sb = (bz == 0) ? S0 : (bz == 1) ? S1 : (bz == 2) ? S2 : S3;
    const int t = threadIdx.x, w = t>>6, L = t&63;
    const int wm = 128*(w>>2), wn = 64*(w&3);
    const int cl = L&15, rq = (L>>4)*4;
    #pragma unroll
    for (int p = 0; p < 2; ++p) {
        const int nt0 = 2*p, nt1 = 2*p+1;
        #pragma unroll
        for (int i = 0; i < 8; ++i) {
            int row0 = m0 + wm + i*16 + rq;
            #pragma unroll
            for (int r = 0; r < 4; ++r) {
                float v0 = acc[i][nt0][r], v1 = acc[i][nt1][r];
                float x0 = __shfl_xor(v0, 1, 64);
                float x1 = __shfl_xor(v1, 1, 64);
                unsigned wv; int colb;
                if ((cl & 1) == 0) {
                    wv   = (unsigned)f2bf(v0) | ((unsigned)f2bf(x0) << 16);
                    colb = nt0*16 + cl;
                } else {
                    wv   = (unsigned)f2bf(x1) | ((unsigned)f2bf(v1) << 16);
                    colb = nt1*16 + (cl-1);
                }
                *(unsigned*)&Sb[(size_t)(row0 + r)*SEQ + n0 + wn + colb] = wv;
            }
        }
    }
}

// ---------------------------------------------------------------------------
// Row softmax over bf16 S (pre-scaled scores), P bf16 in place. 16384 rows.
// ---------------------------------------------------------------------------
__global__ __launch_bounds__(256)
void softmax_pack(u16* __restrict__ S0, u16* __restrict__ S1,
                  u16* __restrict__ S2, u16* __restrict__ S3)
{
    __shared__ float red[4];
    const int t = threadIdx.x, L = t & 63, w = t >> 6;
    const int gr = blockIdx.x, bz = gr >> 12, rr = gr & (SEQ-1);
    u16* Sb = (bz == 0) ? S0 : (bz == 1) ? S1 : (bz == 2) ? S2 : S3;
    u16* row = Sb + (size_t)rr*SEQ;

    float v[16];
    float m = -1e30f;
    #pragma unroll
    for (int j = 0; j < 2; ++j) {
        ushort4 x0 = *(const ushort4*)&row[t*8 + j*2048];
        ushort4 x1 = *(const ushort4*)&row[t*8 + j*2048 + 4];
        union { unsigned u; float f; } c;
        c.u = (unsigned)x0.x << 16; v[8*j+0] = c.f;
        c.u = (unsigned)x0.y << 16; v[8*j+1] = c.f;
        c.u = (unsigned)x0.z << 16; v[8*j+2] = c.f;
        c.u = (unsigned)x0.w << 16; v[8*j+3] = c.f;
        c.u = (unsigned)x1.x << 16; v[8*j+4] = c.f;
        c.u = (unsigned)x1.y << 16; v[8*j+5] = c.f;
        c.u = (unsigned)x1.z << 16; v[8*j+6] = c.f;
        c.u = (unsigned)x1.w << 16; v[8*j+7] = c.f;
    }
    #pragma unroll
    for (int i = 0; i < 16; ++i) m = fmaxf(m, v[i]);
    #pragma unroll
    for (int off = 32; off; off >>= 1) m = fmaxf(m, __shfl_xor(m, off, 64));
    if (L == 0) red[w] = m;
    __syncthreads();
    m = fmaxf(fmaxf(red[0],red[1]), fmaxf(red[2],red[3]));

    float s = 0.f;
    #pragma unroll
    for (int i = 0; i < 16; ++i) { v[i] = __expf(v[i] - m); s += v[i]; }
    #pragma unroll
    for (int off = 32; off; off >>= 1) s += __shfl_xor(s, off, 64);
    __syncthreads();
    if (L == 0) red[w] = s;
    __syncthreads();
    s = red[0]+red[1]+red[2]+red[3];
    const float inv = 1.0f / s;

    #pragma unroll
    for (int j = 0; j < 2; ++j) {
        ushort4 h0, h1;
        h0.x = f2bf(v[8*j+0]*inv); h0.y = f2bf(v[8*j+1]*inv);
        h0.z = f2bf(v[8*j+2]*inv); h0.w = f2bf(v[8*j+3]*inv);
        h1.x = f2bf(v[8*j+4]*inv); h1.y = f2bf(v[8*j+5]*inv);
        h1.z = f2bf(v[8*j+6]*inv); h1.w = f2bf(v[8*j+7]*inv);
        *(ushort4*)&row[t*8 + j*2048]     = h0;
        *(ushort4*)&row[t*8 + j*2048 + 4] = h1;
    }
}

// ---------------------------------------------------------------------------
// PV, all batches: O_b = P_b @ Vt_b^T -> fp32 (scalar stores = full lines)
// ---------------------------------------------------------------------------
__global__ __launch_bounds__(512,2)
void gemm_pv(const u16* __restrict__ P0, const u16* __restrict__ P1,
             const u16* __restrict__ P2, const u16* __restrict__ P3,
             const u16* __restrict__ Vth,
             float* __restrict__ O0, float* __restrict__ O1,
             float* __restrict__ O2, float* __restrict__ O3)
{
    __shared__ __align__(16) u16 lds[65536];
    f32x4 acc[8][4];
    #pragma unroll
    for (int i=0;i<8;++i)
        #pragma unroll
        for (int j=0;j<4;++j) acc[i][j] = (f32x4){0.f,0.f,0.f,0.f};

    const int bz = blockIdx.z;
    const u16* Pb = (bz == 0) ? P0 : (bz == 1) ? P1 : (bz == 2) ? P2 : P3;
    float*     Ob = (bz == 0) ? O0 : (bz == 1) ? O1 : (bz == 2) ? O2 : O3;
    const int m0 = blockIdx.y*256, n0 = blockIdx.x*256;
    gemm256(Pb, SEQ, Vth + (size_t)bz*DIM*SEQ, SEQ, SEQ, m0, n0, lds, acc);

    const int t = threadIdx.x, w = t>>6, L = t&63;
    const int wm = 128*(w>>2), wn = 64*(w&3);
    const int cl = L&15, rq = (L>>4)*4;
    #pragma unroll
    for (int j = 0; j < 4; ++j) {
        int col = n0 + wn + j*16 + cl;
        #pragma unroll
        for (int i = 0; i < 8; ++i) {
            int row0 = m0 + wm + i*16 + rq;
            #pragma unroll
            for (int r = 0; r < 4; ++r)
                Ob[(size_t)(row0 + r)*DIM + col] = acc[i][j][r];
        }
    }
}

// ---------------------------------------------------------------------------
// linear copy (float4), for O2/O3 parked in ws -> d_out second half
// ---------------------------------------------------------------------------
__global__ __launch_bounds__(256)
void copy_out(const float* __restrict__ src, float* __restrict__ dst)
{
    size_t i = ((size_t)blockIdx.x*256 + threadIdx.x)*4;
    *(float4*)&dst[i] = *(const float4*)&src[i];
}

// ---------------------------------------------------------------------------
extern "C" void kernel_launch(void* const* d_in, const int* in_sizes, int n_in,
                              void* d_out, int out_size, void* d_ws, size_t ws_size,
                              hipStream_t stream) {
    const float* X    = (const float*)d_in[0];
    const float* W    = (const float*)d_in[1];
    const float* bias = (const float*)d_in[2];
    float* out = (float*)d_out;

    const size_t MB = (size_t)1 << 20;
    if (ws_size < 192*MB) return;
    char* ws = (char*)d_ws;
    char* wo = (char*)d_out;
    // ws: Qh[0,32) Kh[32,64) Vth[64,96) S0[96,128) S1[128,160) S2[160,192)
    u16* Qh  = (u16*)ws;
    u16* Kh  = (u16*)(ws + 32*MB);
    u16* Vth = (u16*)(ws + 64*MB);
    u16* S0  = (u16*)(ws + 96*MB);
    u16* S1  = (u16*)(ws + 128*MB);
    u16* S2  = (u16*)(ws + 160*MB);
    // d_out during prologue: Xbf[0,32) Wbf[32,38); during attention: S3[32,64)
    u16* Xbf = (u16*)wo;
    u16* Wbf = (u16*)(wo + 32*MB);
    u16* S3  = (u16*)(wo + 32*MB);
    // pv outputs: O0,O1 -> d_out[0,32); O2,O3 -> dead Qh/Kh-front ws[0,32)
    float* O0 = (float*)wo;
    float* O1 = (float*)(wo + 16*MB);
    float* O2 = (float*)ws;
    float* O3 = (float*)(ws + 16*MB);

    cvt_bf16<<<MTOT*DIM/1024, 256, 0, stream>>>(X, Xbf);
    cvt_bf16<<<E3*DIM/1024,   256, 0, stream>>>(W, Wbf);

    gemm_qkv<<<dim3(E3/256, MTOT/256), 512, 0, stream>>>(
        Xbf, Wbf, bias, Qh, Kh, Vth);

    gemm_scores<<<dim3(SEQ/256, SEQ/256, BATCH), 512, 0, stream>>>(
        Qh, Kh, S0, S1, S2, S3);

    softmax_pack<<<MTOT, 256, 0, stream>>>(S0, S1, S2, S3);

    gemm_pv<<<dim3(DIM/256, SEQ/256, BATCH), 512, 0, stream>>>(
        S0, S1, S2, S3, Vth, O0, O1, O2, O3);

    // O2,O3 (32 MB in ws) -> d_out[32,64)
    copy_out<<<(32*MB/sizeof(float))/1024, 256, 0, stream>>>(
        (const float*)ws, out + 8*MB);   // 8M floats = 32 MB offset
}